// Round 8
// baseline (145.409 us; speedup 1.0000x reference)
//
#include <hip/hip_runtime.h>
#include <math.h>
#include <float.h>

#define NPix 3600
#define NC   256
#define NB   4
#define MCAP 768

typedef __attribute__((ext_vector_type(8))) _Float16 half8v;
typedef __attribute__((ext_vector_type(4))) float float4v;

__device__ __forceinline__ unsigned short f2h(float x) {
  _Float16 h = (_Float16)x;           // RTNE
  unsigned short u; __builtin_memcpy(&u, &h, 2); return u;
}
__device__ __forceinline__ float h2f(unsigned short u) {
  _Float16 h; __builtin_memcpy(&h, &u, 2); return (float)h;
}

// async global->LDS DMA, 16B per lane; LDS dest must be wave-uniform base
__device__ __forceinline__ void gld_lds16(const void* g, void* l) {
  __builtin_amdgcn_global_load_lds(
      (const __attribute__((address_space(1))) unsigned int*)g,
      (__attribute__((address_space(3))) unsigned int*)l, 16, 0, 0);
}

// ---------------- K0 (small-ws fallback only): column L2 norms --------------
__global__ __launch_bounds__(256) void k_colnorm(const float* __restrict__ feature,
                                                 float* __restrict__ colnorm) {
  int b = blockIdx.y;
  int n = blockIdx.x * 256 + threadIdx.x;
  if (n >= NPix) return;
  const float* feat = feature + (size_t)b * NC * NPix;
  float acc = 0.f;
#pragma unroll 8
  for (int c = 0; c < NC; ++c) {
    float v = feat[(size_t)c * NPix + n];
    acc += v * v;
  }
  colnorm[b * NPix + n] = sqrtf(acc);
}

// ---------------- top-12 fallback (block-wide iterative argmax) -------------
__device__ void block_top12(const float* __restrict__ p, int t,
                            float* s_rv, int* s_ri, int* s_chosen) {
  for (int k = 0; k < 12; ++k) {
    float best = -FLT_MAX;
    int bi = 0x7fffffff;
    for (int n = t; n < NPix; n += 256) {
      bool excl = false;
      for (int j = 0; j < k; ++j)
        if (s_chosen[j] == n) excl = true;
      if (!excl) {
        float v = p[n];
        if (v > best || (v == best && n < bi)) { best = v; bi = n; }
      }
    }
    s_rv[t] = best; s_ri[t] = bi;
    __syncthreads();
    for (int d = 128; d > 0; d >>= 1) {
      if (t < d) {
        if (s_rv[t + d] > s_rv[t] ||
            (s_rv[t + d] == s_rv[t] && s_ri[t + d] < s_ri[t])) {
          s_rv[t] = s_rv[t + d]; s_ri[t] = s_ri[t + d];
        }
      }
      __syncthreads();
    }
    if (t == 0) s_chosen[k] = s_ri[0];
    __syncthreads();
  }
  if (t == 0) {
    for (int a = 1; a < 12; ++a) {
      int key = s_chosen[a]; int j = a - 1;
      while (j >= 0 && s_chosen[j] > key) { s_chosen[j + 1] = s_chosen[j]; --j; }
      s_chosen[j + 1] = key;
    }
  }
  __syncthreads();
}

// ---------------- K1: masks + deterministic compaction (ballot scan) --------
__global__ __launch_bounds__(256) void k_mask(const float* __restrict__ mask_q,
                                              unsigned char* __restrict__ fgm,
                                              unsigned char* __restrict__ bgm,
                                              int* __restrict__ bgsel,
                                              int* __restrict__ cnts) {
  int b = blockIdx.x;
  int t = threadIdx.x;
  int wv = t >> 6, l = t & 63;
  const float* pred_bg = mask_q + (size_t)b * 2 * NPix;
  const float* pred_fg = pred_bg + NPix;

  __shared__ int   s_wtot[4];
  __shared__ int   s_base[2];
  __shared__ float s_rv[256];
  __shared__ int   s_ri[256];
  __shared__ int   s_chosen[12];

  if (t == 0) { s_base[0] = 0; s_base[1] = 0; }
  __syncthreads();

  unsigned long long lmask = (1ull << l) - 1ull;

  for (int chunk = 0; chunk < NPix; chunk += 256) {
    int n = chunk + t;
    int fgf = 0, bgf = 0;
    if (n < NPix) {
      fgf = pred_fg[n] > 0.5f ? 1 : 0;
      bgf = pred_bg[n] > 0.8f ? 1 : 0;
      fgm[b * NPix + n] = (unsigned char)fgf;
      bgm[b * NPix + n] = (unsigned char)bgf;
    }
    unsigned long long fb = __ballot(fgf != 0);
    unsigned long long bb = __ballot(bgf != 0);
    if (l == 0) s_wtot[wv] = __popcll(fb) | (__popcll(bb) << 16);
    __syncthreads();
    int fsum = 0, bsum = 0, bpre = 0;
#pragma unroll
    for (int w = 0; w < 4; ++w) {
      int v = s_wtot[w];
      if (w < wv) bpre += (v >> 16);
      fsum += v & 0xffff; bsum += (v >> 16);
    }
    if (bgf) {
      int pos = s_base[1] + bpre + (int)__popcll(bb & lmask);
      bgsel[b * NPix + pos] = n;
    }
    __syncthreads();
    if (t == 0) { s_base[0] += fsum; s_base[1] += bsum; }
  }
  __syncthreads();
  int fgcnt = s_base[0];
  int bgcnt = s_base[1];

  if (fgcnt == 0) {
    block_top12(pred_fg, t, s_rv, s_ri, s_chosen);
    if (t < 12) fgm[b * NPix + s_chosen[t]] = 1;
    fgcnt = 12;
    __syncthreads();
  }
  if (bgcnt == 0) {
    block_top12(pred_bg, t, s_rv, s_ri, s_chosen);
    if (t < 12) {
      bgm[b * NPix + s_chosen[t]] = 1;
      bgsel[b * NPix + t] = s_chosen[t];
    }
    bgcnt = 12;
    __syncthreads();
  }
  if (t == 0) { cnts[b] = fgcnt; cnts[4 + b] = bgcnt; }
}

// ---------------- K2 (small-ws fallback only): prototypes -------------------
__global__ __launch_bounds__(256) void k_proto(const float* __restrict__ feature,
                                               const unsigned char* __restrict__ fgm,
                                               const unsigned char* __restrict__ bgm,
                                               const int* __restrict__ cnts,
                                               float* __restrict__ out,
                                               float* __restrict__ bgproto) {
  int c = blockIdx.x, b = blockIdx.y, t = threadIdx.x;
  const float* frow = feature + ((size_t)b * NC + c) * NPix;
  float fs = 0.f, bs = 0.f;
  for (int n = t; n < NPix; n += 256) {
    float v = frow[n];
    fs += v * (float)fgm[b * NPix + n];
    bs += v * (float)bgm[b * NPix + n];
  }
  __shared__ float s1[256], s2[256];
  s1[t] = fs; s2[t] = bs;
  __syncthreads();
  for (int d = 128; d > 0; d >>= 1) {
    if (t < d) { s1[t] += s1[t + d]; s2[t] += s2[t + d]; }
    __syncthreads();
  }
  if (t == 0) {
    out[b * NC + c]     = s1[0] / (float)cnts[b];
    bgproto[b * NC + c] = s2[0] / (float)cnts[4 + b];
  }
}

// ---------------- K3: fused colnorm + fp16 pack + proto partials ------------
__global__ __launch_bounds__(256) void k_normpack(const float* __restrict__ feature,
                                                  const unsigned char* __restrict__ fgm,
                                                  const unsigned char* __restrict__ bgm,
                                                  float* __restrict__ colnorm,
                                                  unsigned short* __restrict__ Qf,
                                                  float* __restrict__ pp) {
  int b = blockIdx.y, nt = blockIdx.x, t = threadIdx.x;
  int n0 = nt * 64;
  __shared__ float s_sq[16][68];
  __shared__ float s_inv[64];
  __shared__ float s_fg[64], s_bg[64];
  __shared__ unsigned int tl[64][65];
  __shared__ float traw[64][65];
  __shared__ float s_red[2][4][64];
  const float* fb = feature + (size_t)b * NC * NPix;

  // phase A: sum of squares
  int p4 = t & 15, cq = t >> 4;
  float sq0 = 0.f, sq1 = 0.f, sq2 = 0.f, sq3 = 0.f;
  if (n0 + 64 <= NPix) {
#pragma unroll
    for (int j = 0; j < 16; ++j) {
      const float* src = fb + (size_t)(cq * 16 + j) * NPix + n0 + p4 * 4;
      float4 v = *(const float4*)src;
      sq0 += v.x * v.x; sq1 += v.y * v.y; sq2 += v.z * v.z; sq3 += v.w * v.w;
    }
  } else {
#pragma unroll
    for (int j = 0; j < 16; ++j) {
      size_t base = (size_t)(cq * 16 + j) * NPix;
      int n = n0 + p4 * 4;
      float v0 = (n + 0 < NPix) ? fb[base + n + 0] : 0.f;
      float v1 = (n + 1 < NPix) ? fb[base + n + 1] : 0.f;
      float v2 = (n + 2 < NPix) ? fb[base + n + 2] : 0.f;
      float v3 = (n + 3 < NPix) ? fb[base + n + 3] : 0.f;
      sq0 += v0 * v0; sq1 += v1 * v1; sq2 += v2 * v2; sq3 += v3 * v3;
    }
  }
  s_sq[cq][p4 * 4 + 0] = sq0;
  s_sq[cq][p4 * 4 + 1] = sq1;
  s_sq[cq][p4 * 4 + 2] = sq2;
  s_sq[cq][p4 * 4 + 3] = sq3;
  __syncthreads();
  if (t < 64) {
    float acc = 0.f;
#pragma unroll
    for (int q = 0; q < 16; ++q) acc += s_sq[q][t];
    float nrm = sqrtf(acc);
    int n = n0 + t;
    s_inv[t] = (n < NPix) ? 1.f / nrm : 0.f;
    if (n < NPix) colnorm[b * NPix + n] = nrm;
    s_fg[t] = (n < NPix) ? (float)fgm[b * NPix + n] : 0.f;
    s_bg[t] = (n < NPix) ? (float)bgm[b * NPix + n] : 0.f;
  }
  __syncthreads();

  // phase B
  unsigned short* QfB = Qf + (size_t)b * NPix * NC;
  int nl = t & 63;
  int nn = n0 + nl;
  bool inr = nn < NPix;
  float invn = s_inv[nl];
  for (int cs = 0; cs < 4; ++cs) {
    int c0 = cs * 64;
#pragma unroll
    for (int i = 0; i < 16; ++i) {
      int cl = (t >> 6) + 4 * i;
      float raw = inr ? fb[(size_t)(c0 + cl) * NPix + nn] : 0.f;
      traw[cl][nl] = raw;
      tl[cl][nl] = (unsigned int)f2h(raw * invn);
    }
    __syncthreads();
#pragma unroll
    for (int i = 0; i < 8; ++i) {
      int idx = t + 256 * i;
      int n = idx >> 5;
      int cp = idx & 31;
      int row = n0 + n;
      if (row < NPix) {
        unsigned int u = (tl[2 * cp][n] & 0xffffu) | (tl[2 * cp + 1][n] << 16);
        *(unsigned int*)&QfB[(size_t)row * NC + c0 + 2 * cp] = u;
      }
    }
    {
      int cl = t & 63, pq = t >> 6;
      float pf = 0.f, pb = 0.f;
#pragma unroll
      for (int k = 0; k < 16; ++k) {
        int p = pq * 16 + k;
        float feat = traw[cl][p];
        pf += feat * s_fg[p];
        pb += feat * s_bg[p];
      }
      s_red[0][pq][cl] = pf;
      s_red[1][pq][cl] = pb;
    }
    __syncthreads();
    if (t < 128) {
      int m = t >> 6, cl = t & 63;
      float s = s_red[m][0][cl] + s_red[m][1][cl] + s_red[m][2][cl] + s_red[m][3][cl];
      pp[((size_t)(b * 57 + nt) * 2 + m) * 256 + c0 + cl] = s;
    }
    __syncthreads();
  }
}

// ---------------- K3b: reduce proto partials -> FP_1 + bgproto --------------
__global__ __launch_bounds__(256) void k_protored(const float* __restrict__ pp,
                                                  const int* __restrict__ cnts,
                                                  float* __restrict__ out,
                                                  float* __restrict__ bgproto) {
  int b = blockIdx.x, c = threadIdx.x;
  float f = 0.f, g = 0.f;
  for (int nt = 0; nt < 57; ++nt) {
    const float* base = pp + (size_t)(b * 57 + nt) * 2 * 256;
    f += base[c];
    g += base[256 + c];
  }
  out[b * NC + c]     = f / (float)cnts[b];
  bgproto[b * NC + c] = g / (float)cnts[4 + b];
}

// ---------------- K4: build V^T fp16 global [256][768] ----------------------
__global__ __launch_bounds__(256) void k_vt(const unsigned short* __restrict__ Qf,
                                            const float* __restrict__ colnorm,
                                            const int* __restrict__ cnts,
                                            const int* __restrict__ bgsel,
                                            unsigned short* __restrict__ Vg) {
  int b = blockIdx.z; int M = cnts[4 + b]; if (M > MCAP) return;
  int jt = blockIdx.x, cs = blockIdx.y, t = threadIdx.x;
  int j0 = jt * 64, c0 = cs * 64;
  __shared__ unsigned short tl[64][73];
  const size_t qoff = (size_t)b * NPix * NC;
#pragma unroll
  for (int i = 0; i < 16; ++i) {
    int idx = t + 256 * i; int j = idx >> 6, ch = idx & 63;
    int jg = j0 + j;
    float v = 0.f;
    if (jg < M) {
      int src = bgsel[b * NPix + jg];
      v = h2f(Qf[qoff + (size_t)src * NC + c0 + ch]) * colnorm[b * NPix + src];
    }
    tl[j][ch] = f2h(v);
  }
  __syncthreads();
#pragma unroll
  for (int i = 0; i < 16; ++i) {
    int idx = t + 256 * i; int ch = idx >> 6, j = idx & 63;
    Vg[((size_t)b * NC + c0 + ch) * MCAP + j0 + j] = tl[j][ch];
  }
}

// ---------------- K5: fused flash-style S->softmax->PV + epilogue -----------
// Block: 64 q-rows x 128 out-channels. Q tile resident (32 KB); per 64-j tile:
// stage gathered B tile (32 KB, gld_lds + source-side slot swizzle), S via
// MFMA (ascending k, bit-identical to the 2-kernel path), w=exp(2s-2) in regs,
// C-layout -> A-layout via 8 KB swizzled LDS (aliases B's first 8 KB after S
// reads), PV with V^T fragments from global Vg. Row denominators accumulate in
// registers (PV C-layout rows == S C-layout rows); epilogue transposes via LDS.
__global__ __launch_bounds__(256, 2) void k_fused(const unsigned short* __restrict__ Qf,
                                                  const unsigned short* __restrict__ Vg,
                                                  const int* __restrict__ cnts,
                                                  const int* __restrict__ bgsel,
                                                  const float* __restrict__ bgproto,
                                                  float* __restrict__ out) {
  int b = blockIdx.z; int M = cnts[4 + b]; if (M > MCAP) return;
  int rt = blockIdx.x, cs = blockIdx.y;
  int t = threadIdx.x, wv = t >> 6, l = t & 63;
  int n0 = rt * 64, c0 = cs * 128;
  int lr = l & 15, lk = l >> 4;

  __shared__ __align__(16) char smem[65536];
  unsigned short* Qt = (unsigned short*)smem;            // [64][256], 32 slots/row
  unsigned short* Bt = (unsigned short*)(smem + 32768);  // [64][256]
  unsigned short* Wt = (unsigned short*)(smem + 32768);  // alias: [64][64], 8 slots/row

  const unsigned short* QfB = Qf + (size_t)b * NPix * NC;

  // ---- stage Q tile (once): LDS[row][phys] = global slot (phys ^ (row&7)) ----
#pragma unroll
  for (int i = 0; i < 8; ++i) {
    int u = i * 256 + wv * 64 + l;
    int r = u >> 5, ps = u & 31;
    int grow = n0 + r; if (grow > NPix - 1) grow = NPix - 1;
    gld_lds16(QfB + (size_t)grow * NC + ((ps ^ (r & 7)) << 3),
              smem + (size_t)(i * 256 + wv * 64) * 16);
  }

  // B stage descriptors (row index + swizzled source slot offset per issue)
  int bri[8], bso[8];
#pragma unroll
  for (int i = 0; i < 8; ++i) {
    int u = i * 256 + wv * 64 + l;
    int r = u >> 5, ps = u & 31;
    bri[i] = r;
    bso[i] = (ps ^ (r & 7)) << 3;
  }

#define STAGEB(j0_) do {                                                      \
    _Pragma("unroll")                                                         \
    for (int i_ = 0; i_ < 8; ++i_) {                                          \
      int jg_ = (j0_) + bri[i_];                                              \
      int src_ = (jg_ < M) ? bgsel[b * NPix + jg_] : 0;                       \
      gld_lds16(QfB + (size_t)src_ * NC + bso[i_],                            \
                smem + 32768 + (size_t)(i_ * 256 + wv * 64) * 16);            \
    }                                                                         \
  } while (0)

  STAGEB(0);

  float4v accO[8];
#pragma unroll
  for (int cf = 0; cf < 8; ++cf) { float4v z = {0.f,0.f,0.f,0.f}; accO[cf] = z; }
  float lacc[4] = {0.f, 0.f, 0.f, 0.f};

  int qrow = wv * 16 + lr;       // A-operand row (S and PV), block-local
  int qxr = qrow & 7;
  const unsigned short* vbase = Vg + ((size_t)b * NC + c0 + lr) * MCAP + lk * 8;

  int njt = (M + 63) >> 6;
  __syncthreads();               // Q tile + first B tile DMA drained

  for (int jt = 0; jt < njt; ++jt) {
    int j0 = jt * 64;
    // ---- S phase: 8 k-steps x 4 j-fragments (ascending k == 2-kernel path) --
    float4v accS[4];
#pragma unroll
    for (int cf = 0; cf < 4; ++cf) { float4v z = {0.f,0.f,0.f,0.f}; accS[cf] = z; }
#pragma unroll
    for (int kst = 0; kst < 8; ++kst) {
      int ls = kst * 4 + lk;
      half8v a = *(const half8v*)&Qt[qrow * 256 + ((ls ^ qxr) << 3)];
#pragma unroll
      for (int cf = 0; cf < 4; ++cf) {
        int j = cf * 16 + lr;
        half8v bb = *(const half8v*)&Bt[j * 256 + ((ls ^ (j & 7)) << 3)];
        accS[cf] = __builtin_amdgcn_mfma_f32_16x16x32_f16(a, bb, accS[cf], 0, 0, 0);
      }
    }
    __syncthreads();     // all S reads of Bt done -> Wt (alias) writable

    // ---- w phase: exp in regs, write swizzled Wt, accumulate row sums ------
#pragma unroll
    for (int cf = 0; cf < 4; ++cf) {
      int jl = cf * 16 + lr;
      int jg = j0 + jl;
      int slot = jl >> 3;
#pragma unroll
      for (int i = 0; i < 4; ++i) {
        int rl = wv * 16 + lk * 4 + i;
        float s = accS[cf][i];
        unsigned short w16 = (jg < M) ? f2h(__expf(2.f * s - 2.f)) : (unsigned short)0;
        Wt[rl * 64 + ((slot ^ (rl & 7)) << 3) + (jl & 7)] = w16;
        lacc[i] += h2f(w16);
      }
    }
    __syncthreads();     // Wt visible

    // ---- PV phase: A = w from Wt, B = V^T fragments from global Vg ---------
#pragma unroll
    for (int kk = 0; kk < 2; ++kk) {
      int ls = kk * 4 + lk;
      half8v aw = *(const half8v*)&Wt[qrow * 64 + ((ls ^ qxr) << 3)];
      const unsigned short* vp = vbase + j0 + kk * 32;
#pragma unroll
      for (int cf = 0; cf < 8; ++cf) {
        half8v bv = *(const half8v*)(vp + (size_t)cf * 16 * MCAP);
        accO[cf] = __builtin_amdgcn_mfma_f32_16x16x32_f16(aw, bv, accO[cf], 0, 0, 0);
      }
    }
    __syncthreads();     // Wt reads done -> B region writable
    if (jt + 1 < njt) STAGEB(j0 + 64);
    __syncthreads();     // drain DMA -> Bt ready
  }
#undef STAGEB

  // ---- denominators: reduce over the 16-lane j-groups ----
#pragma unroll
  for (int i = 0; i < 4; ++i) {
    lacc[i] += __shfl_xor(lacc[i], 1);
    lacc[i] += __shfl_xor(lacc[i], 2);
    lacc[i] += __shfl_xor(lacc[i], 4);
    lacc[i] += __shfl_xor(lacc[i], 8);
  }
  float linv[4];
#pragma unroll
  for (int i = 0; i < 4; ++i) linv[i] = 1.f / lacc[i];

  // ---- epilogue: two 64-channel halves through an LDS transpose ----
  float* trans = (float*)smem;   // [64][65] f32 = 16.6 KB, aliases dead Qt
  float* outBP = out + NB * NC;
#pragma unroll
  for (int half = 0; half < 2; ++half) {
    __syncthreads();
#pragma unroll
    for (int cfl = 0; cfl < 4; ++cfl) {
      int cf = half * 4 + cfl;
      int c_l = cfl * 16 + lr;
#pragma unroll
      for (int i = 0; i < 4; ++i) {
        int rl = wv * 16 + lk * 4 + i;
        trans[c_l * 65 + rl] = accO[cf][i] * linv[i] * 0.7f;
      }
    }
    __syncthreads();
#pragma unroll
    for (int it = 0; it < 4; ++it) {
      int idx = t + 256 * it;      // 0..1023
      int c_l = idx >> 4;          // 0..63
      int q   = idx & 15;          // n-quad 0..15
      int n   = n0 + q * 4;
      if (n < NPix) {              // NPix%4==0 -> whole quad in range
        float bpv = bgproto[b * NC + c0 + half * 64 + c_l] * 0.3f;
        float4 o;
        o.x = bpv + trans[c_l * 65 + q * 4 + 0];
        o.y = bpv + trans[c_l * 65 + q * 4 + 1];
        o.z = bpv + trans[c_l * 65 + q * 4 + 2];
        o.w = bpv + trans[c_l * 65 + q * 4 + 3];
        *(float4*)&outBP[((size_t)b * NC + c0 + half * 64 + c_l) * NPix + n] = o;
      }
    }
  }
}

// ---------------- fallback: gather + fp32 attention (gated) -----------------
__global__ __launch_bounds__(256) void k_gather(const float* __restrict__ feature,
                                                const float* __restrict__ colnorm,
                                                const int* __restrict__ cnts,
                                                const int* __restrict__ bgsel,
                                                float* __restrict__ featn_sel,
                                                float* __restrict__ normsel,
                                                int gate) {
  int b = blockIdx.y;
  int cnt = cnts[4 + b];
  if (gate && cnt <= MCAP) return;
  int jl = threadIdx.x >> 6;
  int lane = threadIdx.x & 63;
  int j = blockIdx.x * 4 + jl;
  if (j >= cnt) return;
  int row = bgsel[b * NPix + j];
  float nrm = colnorm[b * NPix + row];
  float inv = 1.f / nrm;
#pragma unroll
  for (int i = 0; i < 4; ++i) {
    int c = lane + 64 * i;
    featn_sel[((size_t)b * NPix + j) * NC + c] =
        feature[((size_t)b * NC + c) * NPix + row] * inv;
  }
  if (lane == 0) normsel[b * NPix + j] = nrm;
}

__global__ __launch_bounds__(256) void k_attn(const float* __restrict__ feature,
                                              const float* __restrict__ colnorm,
                                              const int* __restrict__ cnts,
                                              const float* __restrict__ featn_sel,
                                              const float* __restrict__ normsel,
                                              const float* __restrict__ bgproto,
                                              float* __restrict__ out,
                                              int gate) {
  int b = blockIdx.y;
  int M = cnts[4 + b];
  if (gate && M <= MCAP) return;
  int tile = blockIdx.x;
  int t = threadIdx.x;
  int rl  = t >> 4;
  int l16 = t & 15;
  int row = tile * 16 + rl;
  const float* feat = feature + (size_t)b * NC * NPix;

  __shared__ float s_k[32][NC];
  __shared__ float s_vn[32];

  float inv_n = 1.f / colnorm[b * NPix + row];
  float q[16];
#pragma unroll
  for (int k = 0; k < 4; ++k)
#pragma unroll
    for (int i = 0; i < 4; ++i) {
      int c = l16 * 4 + 64 * k + i;
      q[k * 4 + i] = feat[(size_t)c * NPix + row] * inv_n;
    }

  float l_acc = 0.f;
  float O[16];
#pragma unroll
  for (int i = 0; i < 16; ++i) O[i] = 0.f;

  for (int kt = 0; kt < M; kt += 32) {
    int jmax = min(32, M - kt);
    __syncthreads();
    for (int u = t; u < 32 * 64; u += 256) {
      int jj = u >> 6;
      int cc = (u & 63) << 2;
      if (jj < jmax)
        *(float4*)&s_k[jj][cc] =
            *(const float4*)&featn_sel[((size_t)b * NPix + kt + jj) * NC + cc];
    }
    if (t < 32) s_vn[t] = (t < jmax) ? normsel[b * NPix + kt + t] : 0.f;
    __syncthreads();

    for (int j = 0; j < jmax; ++j) {
      float kv[16];
      float s = 0.f;
#pragma unroll
      for (int k = 0; k < 4; ++k) {
        float4 v4 = *(const float4*)&s_k[j][l16 * 4 + 64 * k];
        kv[k * 4 + 0] = v4.x; kv[k * 4 + 1] = v4.y;
        kv[k * 4 + 2] = v4.z; kv[k * 4 + 3] = v4.w;
        s += q[k * 4 + 0] * v4.x + q[k * 4 + 1] * v4.y +
             q[k * 4 + 2] * v4.z + q[k * 4 + 3] * v4.w;
      }
      s += __shfl_xor(s, 1);
      s += __shfl_xor(s, 2);
      s += __shfl_xor(s, 4);
      s += __shfl_xor(s, 8);
      float e = __expf(2.f * s - 2.f);
      l_acc += e;
      float ev = e * s_vn[j];
#pragma unroll
      for (int i = 0; i < 16; ++i) O[i] += ev * kv[i];
    }
  }

  float inv_l = 1.f / l_acc;
  float* outBP = out + NB * NC;
  const float* bp = bgproto + b * NC;
#pragma unroll
  for (int k = 0; k < 4; ++k)
#pragma unroll
    for (int i = 0; i < 4; ++i) {
      int c = l16 * 4 + 64 * k + i;
      outBP[((size_t)b * NC + c) * NPix + row] =
          bp[c] * 0.3f + O[k * 4 + i] * inv_l * 0.7f;
    }
}

// ---------------------------------------------------------------------------
extern "C" void kernel_launch(void* const* d_in, const int* in_sizes, int n_in,
                              void* d_out, int out_size, void* d_ws, size_t ws_size,
                              hipStream_t stream) {
  const float* feature = (const float*)d_in[0];
  const float* mask_q  = (const float*)d_in[1];
  float* out = (float*)d_out;
  char* ws = (char*)d_ws;

  const size_t BIG_NEED = 24364160ULL;
  if (ws_size >= BIG_NEED) {
    // big-mode carve (all offsets 16B-aligned, sizes in BYTES):
    float* colnorm   = (float*)(ws + 0);          //    57,600
    float* normsel   = (float*)(ws + 57600);      //    57,600 (fallback)
    float* bgproto   = (float*)(ws + 115200);     //     4,096
    int*   cnts      = (int*)  (ws + 119296);     //       256 slot
    int*   bgsel     = (int*)  (ws + 119552);     //    57,600 -> 177,152
    unsigned char* fgm = (unsigned char*)(ws + 177152);    // 14,400
    unsigned char* bgm = (unsigned char*)(ws + 191552);    // 14,400 -> 205,952
    float* pp        = (float*)(ws + 205952);     //   466,944 -> 672,896
    unsigned short* Vg  = (unsigned short*)(ws + 672896);   //  1,572,864 -> 2,245,760
    unsigned short* Qf  = (unsigned short*)(ws + 2245760);  //  7,372,800 -> 9,618,560
    float* featn_sel = (float*)(ws + 9618560);    // 14,745,600 -> 24,364,160 (fallback)

    k_mask    <<<NB,               256, 0, stream>>>(mask_q, fgm, bgm, bgsel, cnts);
    k_normpack<<<dim3(57, NB),     256, 0, stream>>>(feature, fgm, bgm, colnorm, Qf, pp);
    k_protored<<<NB,               256, 0, stream>>>(pp, cnts, out, bgproto);
    k_vt      <<<dim3(12, 4, NB),  256, 0, stream>>>(Qf, colnorm, cnts, bgsel, Vg);
    k_fused   <<<dim3(57, 2, NB),  256, 0, stream>>>(Qf, Vg, cnts, bgsel, bgproto, out);
    // fallback path, active only for batches with M > MCAP
    k_gather  <<<dim3(900, NB),    256, 0, stream>>>(feature, colnorm, cnts, bgsel,
                                                     featn_sel, normsel, 1);
    k_attn    <<<dim3(225, NB),    256, 0, stream>>>(feature, colnorm, cnts, featn_sel,
                                                     normsel, bgproto, out, 1);
  } else {
    // small-ws fallback: round-1 layout + kernels
    float* colnorm  = (float*)(ws + 0);
    float* normsel  = (float*)(ws + 57600);
    float* bgproto  = (float*)(ws + 115200);
    int*   cnts     = (int*)  (ws + 119296);
    int*   bgsel    = (int*)  (ws + 119360);
    unsigned char* fgm = (unsigned char*)(ws + 176960);
    unsigned char* bgm = (unsigned char*)(ws + 191360);
    float* featn_sel = (float*)(ws + 205824);

    k_colnorm<<<dim3(15, NB), 256, 0, stream>>>(feature, colnorm);
    k_mask   <<<NB,           256, 0, stream>>>(mask_q, fgm, bgm, bgsel, cnts);
    k_proto  <<<dim3(NC, NB), 256, 0, stream>>>(feature, fgm, bgm, cnts, out, bgproto);
    k_gather <<<dim3(900, NB),256, 0, stream>>>(feature, colnorm, cnts, bgsel,
                                                featn_sel, normsel, 0);
    k_attn   <<<dim3(225, NB),256, 0, stream>>>(feature, colnorm, cnts, featn_sel,
                                                normsel, bgproto, out, 0);
  }
}

// Round 9
// 106.894 us; speedup vs baseline: 1.3603x; 1.3603x over previous
//
#include <hip/hip_runtime.h>
#include <math.h>
#include <float.h>

#define NPix 3600
#define NC   256
#define NB   4
#define MCAP 768

typedef __attribute__((ext_vector_type(8))) _Float16 half8v;
typedef __attribute__((ext_vector_type(4))) float float4v;

__device__ __forceinline__ unsigned short f2h(float x) {
  _Float16 h = (_Float16)x;           // RTNE
  unsigned short u; __builtin_memcpy(&u, &h, 2); return u;
}
__device__ __forceinline__ float h2f(unsigned short u) {
  _Float16 h; __builtin_memcpy(&h, &u, 2); return (float)h;
}

// async global->LDS DMA, 16B per lane; LDS dest must be wave-uniform base
__device__ __forceinline__ void gld_lds16(const void* g, void* l) {
  __builtin_amdgcn_global_load_lds(
      (const __attribute__((address_space(1))) unsigned int*)g,
      (__attribute__((address_space(3))) unsigned int*)l, 16, 0, 0);
}

// ---------------- K0 (small-ws fallback only): column L2 norms --------------
__global__ __launch_bounds__(256) void k_colnorm(const float* __restrict__ feature,
                                                 float* __restrict__ colnorm) {
  int b = blockIdx.y;
  int n = blockIdx.x * 256 + threadIdx.x;
  if (n >= NPix) return;
  const float* feat = feature + (size_t)b * NC * NPix;
  float acc = 0.f;
#pragma unroll 8
  for (int c = 0; c < NC; ++c) {
    float v = feat[(size_t)c * NPix + n];
    acc += v * v;
  }
  colnorm[b * NPix + n] = sqrtf(acc);
}

// ---------------- top-12 fallback (block-wide iterative argmax) -------------
__device__ void block_top12(const float* __restrict__ p, int t,
                            float* s_rv, int* s_ri, int* s_chosen) {
  for (int k = 0; k < 12; ++k) {
    float best = -FLT_MAX;
    int bi = 0x7fffffff;
    for (int n = t; n < NPix; n += 256) {
      bool excl = false;
      for (int j = 0; j < k; ++j)
        if (s_chosen[j] == n) excl = true;
      if (!excl) {
        float v = p[n];
        if (v > best || (v == best && n < bi)) { best = v; bi = n; }
      }
    }
    s_rv[t] = best; s_ri[t] = bi;
    __syncthreads();
    for (int d = 128; d > 0; d >>= 1) {
      if (t < d) {
        if (s_rv[t + d] > s_rv[t] ||
            (s_rv[t + d] == s_rv[t] && s_ri[t + d] < s_ri[t])) {
          s_rv[t] = s_rv[t + d]; s_ri[t] = s_ri[t + d];
        }
      }
      __syncthreads();
    }
    if (t == 0) s_chosen[k] = s_ri[0];
    __syncthreads();
  }
  if (t == 0) {
    for (int a = 1; a < 12; ++a) {
      int key = s_chosen[a]; int j = a - 1;
      while (j >= 0 && s_chosen[j] > key) { s_chosen[j + 1] = s_chosen[j]; --j; }
      s_chosen[j + 1] = key;
    }
  }
  __syncthreads();
}

// ---------------- K1: masks + deterministic compaction (ballot scan) --------
__global__ __launch_bounds__(256) void k_mask(const float* __restrict__ mask_q,
                                              unsigned char* __restrict__ fgm,
                                              unsigned char* __restrict__ bgm,
                                              int* __restrict__ bgsel,
                                              int* __restrict__ cnts) {
  int b = blockIdx.x;
  int t = threadIdx.x;
  int wv = t >> 6, l = t & 63;
  const float* pred_bg = mask_q + (size_t)b * 2 * NPix;
  const float* pred_fg = pred_bg + NPix;

  __shared__ int   s_wtot[4];
  __shared__ int   s_base[2];
  __shared__ float s_rv[256];
  __shared__ int   s_ri[256];
  __shared__ int   s_chosen[12];

  if (t == 0) { s_base[0] = 0; s_base[1] = 0; }
  __syncthreads();

  unsigned long long lmask = (1ull << l) - 1ull;

  for (int chunk = 0; chunk < NPix; chunk += 256) {
    int n = chunk + t;
    int fgf = 0, bgf = 0;
    if (n < NPix) {
      fgf = pred_fg[n] > 0.5f ? 1 : 0;
      bgf = pred_bg[n] > 0.8f ? 1 : 0;
      fgm[b * NPix + n] = (unsigned char)fgf;
      bgm[b * NPix + n] = (unsigned char)bgf;
    }
    unsigned long long fb = __ballot(fgf != 0);
    unsigned long long bb = __ballot(bgf != 0);
    if (l == 0) s_wtot[wv] = __popcll(fb) | (__popcll(bb) << 16);
    __syncthreads();
    int fsum = 0, bsum = 0, bpre = 0;
#pragma unroll
    for (int w = 0; w < 4; ++w) {
      int v = s_wtot[w];
      if (w < wv) bpre += (v >> 16);
      fsum += v & 0xffff; bsum += (v >> 16);
    }
    if (bgf) {
      int pos = s_base[1] + bpre + (int)__popcll(bb & lmask);
      bgsel[b * NPix + pos] = n;
    }
    __syncthreads();
    if (t == 0) { s_base[0] += fsum; s_base[1] += bsum; }
  }
  __syncthreads();
  int fgcnt = s_base[0];
  int bgcnt = s_base[1];

  if (fgcnt == 0) {
    block_top12(pred_fg, t, s_rv, s_ri, s_chosen);
    if (t < 12) fgm[b * NPix + s_chosen[t]] = 1;
    fgcnt = 12;
    __syncthreads();
  }
  if (bgcnt == 0) {
    block_top12(pred_bg, t, s_rv, s_ri, s_chosen);
    if (t < 12) {
      bgm[b * NPix + s_chosen[t]] = 1;
      bgsel[b * NPix + t] = s_chosen[t];
    }
    bgcnt = 12;
    __syncthreads();
  }
  if (t == 0) { cnts[b] = fgcnt; cnts[4 + b] = bgcnt; }
}

// ---------------- K2 (small-ws fallback only): prototypes -------------------
__global__ __launch_bounds__(256) void k_proto(const float* __restrict__ feature,
                                               const unsigned char* __restrict__ fgm,
                                               const unsigned char* __restrict__ bgm,
                                               const int* __restrict__ cnts,
                                               float* __restrict__ out,
                                               float* __restrict__ bgproto) {
  int c = blockIdx.x, b = blockIdx.y, t = threadIdx.x;
  const float* frow = feature + ((size_t)b * NC + c) * NPix;
  float fs = 0.f, bs = 0.f;
  for (int n = t; n < NPix; n += 256) {
    float v = frow[n];
    fs += v * (float)fgm[b * NPix + n];
    bs += v * (float)bgm[b * NPix + n];
  }
  __shared__ float s1[256], s2[256];
  s1[t] = fs; s2[t] = bs;
  __syncthreads();
  for (int d = 128; d > 0; d >>= 1) {
    if (t < d) { s1[t] += s1[t + d]; s2[t] += s2[t + d]; }
    __syncthreads();
  }
  if (t == 0) {
    out[b * NC + c]     = s1[0] / (float)cnts[b];
    bgproto[b * NC + c] = s2[0] / (float)cnts[4 + b];
  }
}

// ---------------- K3: fused colnorm + fp16 pack + proto partials ------------
__global__ __launch_bounds__(256) void k_normpack(const float* __restrict__ feature,
                                                  const unsigned char* __restrict__ fgm,
                                                  const unsigned char* __restrict__ bgm,
                                                  float* __restrict__ colnorm,
                                                  unsigned short* __restrict__ Qf,
                                                  float* __restrict__ pp) {
  int b = blockIdx.y, nt = blockIdx.x, t = threadIdx.x;
  int n0 = nt * 64;
  __shared__ float s_sq[16][68];
  __shared__ float s_inv[64];
  __shared__ float s_fg[64], s_bg[64];
  __shared__ unsigned int tl[64][65];
  __shared__ float traw[64][65];
  __shared__ float s_red[2][4][64];
  const float* fb = feature + (size_t)b * NC * NPix;

  // phase A: sum of squares
  int p4 = t & 15, cq = t >> 4;
  float sq0 = 0.f, sq1 = 0.f, sq2 = 0.f, sq3 = 0.f;
  if (n0 + 64 <= NPix) {
#pragma unroll
    for (int j = 0; j < 16; ++j) {
      const float* src = fb + (size_t)(cq * 16 + j) * NPix + n0 + p4 * 4;
      float4 v = *(const float4*)src;
      sq0 += v.x * v.x; sq1 += v.y * v.y; sq2 += v.z * v.z; sq3 += v.w * v.w;
    }
  } else {
#pragma unroll
    for (int j = 0; j < 16; ++j) {
      size_t base = (size_t)(cq * 16 + j) * NPix;
      int n = n0 + p4 * 4;
      float v0 = (n + 0 < NPix) ? fb[base + n + 0] : 0.f;
      float v1 = (n + 1 < NPix) ? fb[base + n + 1] : 0.f;
      float v2 = (n + 2 < NPix) ? fb[base + n + 2] : 0.f;
      float v3 = (n + 3 < NPix) ? fb[base + n + 3] : 0.f;
      sq0 += v0 * v0; sq1 += v1 * v1; sq2 += v2 * v2; sq3 += v3 * v3;
    }
  }
  s_sq[cq][p4 * 4 + 0] = sq0;
  s_sq[cq][p4 * 4 + 1] = sq1;
  s_sq[cq][p4 * 4 + 2] = sq2;
  s_sq[cq][p4 * 4 + 3] = sq3;
  __syncthreads();
  if (t < 64) {
    float acc = 0.f;
#pragma unroll
    for (int q = 0; q < 16; ++q) acc += s_sq[q][t];
    float nrm = sqrtf(acc);
    int n = n0 + t;
    s_inv[t] = (n < NPix) ? 1.f / nrm : 0.f;
    if (n < NPix) colnorm[b * NPix + n] = nrm;
    s_fg[t] = (n < NPix) ? (float)fgm[b * NPix + n] : 0.f;
    s_bg[t] = (n < NPix) ? (float)bgm[b * NPix + n] : 0.f;
  }
  __syncthreads();

  // phase B
  unsigned short* QfB = Qf + (size_t)b * NPix * NC;
  int nl = t & 63;
  int nn = n0 + nl;
  bool inr = nn < NPix;
  float invn = s_inv[nl];
  for (int cs = 0; cs < 4; ++cs) {
    int c0 = cs * 64;
#pragma unroll
    for (int i = 0; i < 16; ++i) {
      int cl = (t >> 6) + 4 * i;
      float raw = inr ? fb[(size_t)(c0 + cl) * NPix + nn] : 0.f;
      traw[cl][nl] = raw;
      tl[cl][nl] = (unsigned int)f2h(raw * invn);
    }
    __syncthreads();
#pragma unroll
    for (int i = 0; i < 8; ++i) {
      int idx = t + 256 * i;
      int n = idx >> 5;
      int cp = idx & 31;
      int row = n0 + n;
      if (row < NPix) {
        unsigned int u = (tl[2 * cp][n] & 0xffffu) | (tl[2 * cp + 1][n] << 16);
        *(unsigned int*)&QfB[(size_t)row * NC + c0 + 2 * cp] = u;
      }
    }
    {
      int cl = t & 63, pq = t >> 6;
      float pf = 0.f, pb = 0.f;
#pragma unroll
      for (int k = 0; k < 16; ++k) {
        int p = pq * 16 + k;
        float feat = traw[cl][p];
        pf += feat * s_fg[p];
        pb += feat * s_bg[p];
      }
      s_red[0][pq][cl] = pf;
      s_red[1][pq][cl] = pb;
    }
    __syncthreads();
    if (t < 128) {
      int m = t >> 6, cl = t & 63;
      float s = s_red[m][0][cl] + s_red[m][1][cl] + s_red[m][2][cl] + s_red[m][3][cl];
      pp[((size_t)(b * 57 + nt) * 2 + m) * 256 + c0 + cl] = s;
    }
    __syncthreads();
  }
}

// ---------------- K4: V^T fp16 build + (merged) proto reduce ----------------
// blockIdx.x in [0,11]: V^T tile build; blockIdx.x == 12 (y==0): proto reduce.
__global__ __launch_bounds__(256) void k_vtp(const unsigned short* __restrict__ Qf,
                                             const float* __restrict__ colnorm,
                                             const int* __restrict__ cnts,
                                             const int* __restrict__ bgsel,
                                             unsigned short* __restrict__ Vg,
                                             const float* __restrict__ pp,
                                             float* __restrict__ out,
                                             float* __restrict__ bgproto) {
  int b = blockIdx.z;
  if (blockIdx.x == 12) {
    if (blockIdx.y != 0) return;
    int c = threadIdx.x;
    float f = 0.f, g = 0.f;
    for (int nt = 0; nt < 57; ++nt) {
      const float* base = pp + (size_t)(b * 57 + nt) * 2 * 256;
      f += base[c];
      g += base[256 + c];
    }
    out[b * NC + c]     = f / (float)cnts[b];
    bgproto[b * NC + c] = g / (float)cnts[4 + b];
    return;
  }
  int M = cnts[4 + b]; if (M > MCAP) return;
  int jt = blockIdx.x, cs = blockIdx.y, t = threadIdx.x;
  int j0 = jt * 64, c0 = cs * 64;
  __shared__ unsigned short tl[64][73];
  const size_t qoff = (size_t)b * NPix * NC;
#pragma unroll
  for (int i = 0; i < 16; ++i) {
    int idx = t + 256 * i; int j = idx >> 6, ch = idx & 63;
    int jg = j0 + j;
    float v = 0.f;
    if (jg < M) {
      int src = bgsel[b * NPix + jg];
      v = h2f(Qf[qoff + (size_t)src * NC + c0 + ch]) * colnorm[b * NPix + src];
    }
    tl[j][ch] = f2h(v);
  }
  __syncthreads();
#pragma unroll
  for (int i = 0; i < 16; ++i) {
    int idx = t + 256 * i; int ch = idx >> 6, j = idx & 63;
    Vg[((size_t)b * NC + c0 + ch) * MCAP + j0 + j] = tl[j][ch];
  }
}

// ---------------- K5: GEMM1 fp16 — 128x128 tile, gld_lds + swizzle ----------
// j-tile widened to 128: 32 MFMA per barrier-pair per wave (2x round-7), half
// the blocks/barriers. Same ascending-K order and swizzle math as the proven
// round-7 kernel; LDS 32 KB -> >=4 blocks/CU.
__global__ __launch_bounds__(256) void k_gemm1(const unsigned short* __restrict__ Qf,
                                               const int* __restrict__ cnts,
                                               const int* __restrict__ bgsel,
                                               unsigned short* __restrict__ wbuf,
                                               float* __restrict__ wpart) {
  int b = blockIdx.z;
  int M = cnts[4 + b];
  if (M > MCAP) return;
  int jt = blockIdx.y;
  if (jt * 128 >= M) return;
  int rt = blockIdx.x;
  int t = threadIdx.x, wv = t >> 6, l = t & 63;
  int n0 = rt * 128, j0 = jt * 128;

  __shared__ __align__(16) unsigned short Ah[128][64];   // 16 KB
  __shared__ __align__(16) unsigned short Bh[128][64];   // 16 KB

  const unsigned short* QfB = Qf + (size_t)b * NPix * NC;

  size_t asrc[4];
  int    aslt[4];
#pragma unroll
  for (int i = 0; i < 4; ++i) {
    int u = i * 256 + wv * 64 + l;           // 0..1023
    int r = u >> 3, sl = u & 7;
    int grow = n0 + r; if (grow > NPix - 1) grow = NPix - 1;
    asrc[i] = (size_t)grow * NC;
    aslt[i] = (sl ^ (r & 7)) << 3;
  }
  size_t bsrc[4];
  int    bslt[4];
#pragma unroll
  for (int i = 0; i < 4; ++i) {
    int u = i * 256 + wv * 64 + l;           // 0..1023
    int r = u >> 3, sl = u & 7;
    int jg = j0 + r;
    int src = (jg < M) ? bgsel[b * NPix + jg] : 0;
    bsrc[i] = (size_t)src * NC;
    bslt[i] = (sl ^ (r & 7)) << 3;
  }

  int lr = l & 15;
  int lk = l >> 4;

  float4v acc[2][8];
#pragma unroll
  for (int rf = 0; rf < 2; ++rf)
#pragma unroll
    for (int cf = 0; cf < 8; ++cf) { float4v z = {0.f,0.f,0.f,0.f}; acc[rf][cf] = z; }

  for (int cc = 0; cc < 4; ++cc) {
    int cbase = cc * 64;
#pragma unroll
    for (int i = 0; i < 4; ++i) {
      int ldso = (i * 256 + wv * 64) * 16;
      gld_lds16(QfB + asrc[i] + cbase + aslt[i], (char*)&Ah[0][0] + ldso);
    }
#pragma unroll
    for (int i = 0; i < 4; ++i) {
      int ldso = (i * 256 + wv * 64) * 16;
      gld_lds16(QfB + bsrc[i] + cbase + bslt[i], (char*)&Bh[0][0] + ldso);
    }
    __syncthreads();   // drains vmcnt -> DMA complete

#pragma unroll
    for (int kk = 0; kk < 2; ++kk) {
      int kslot = kk * 4 + lk;
      half8v ah[2];
#pragma unroll
      for (int rf = 0; rf < 2; ++rf) {
        int r = wv * 32 + rf * 16 + lr;
        int s = (kslot ^ (r & 7)) << 3;
        ah[rf] = *(const half8v*)&Ah[r][s];
      }
#pragma unroll
      for (int cf = 0; cf < 8; ++cf) {
        int j = cf * 16 + lr;
        int s = (kslot ^ (j & 7)) << 3;
        half8v bh = *(const half8v*)&Bh[j][s];
#pragma unroll
        for (int rf = 0; rf < 2; ++rf)
          acc[rf][cf] = __builtin_amdgcn_mfma_f32_16x16x32_f16(ah[rf], bh, acc[rf][cf], 0, 0, 0);
      }
    }
    __syncthreads();   // before next-chunk overwrite
  }

  // epilogue: w = exp(2s-2) -> fp16; store + per-row partial sums
  float rs[2][4];
#pragma unroll
  for (int rf = 0; rf < 2; ++rf)
#pragma unroll
    for (int i = 0; i < 4; ++i) rs[rf][i] = 0.f;

#pragma unroll
  for (int rf = 0; rf < 2; ++rf)
#pragma unroll
    for (int cf = 0; cf < 8; ++cf)
#pragma unroll
      for (int i = 0; i < 4; ++i) {
        int row = n0 + wv * 32 + rf * 16 + lk * 4 + i;
        int j = j0 + cf * 16 + lr;
        float s = acc[rf][cf][i];
        unsigned short w16 = (j < M) ? f2h(__expf(2.f * s - 2.f)) : (unsigned short)0;
        if (row < NPix)
          wbuf[((size_t)b * NPix + row) * MCAP + j] = w16;
        rs[rf][i] += h2f(w16);
      }

#pragma unroll
  for (int rf = 0; rf < 2; ++rf)
#pragma unroll
    for (int i = 0; i < 4; ++i) {
      float v = rs[rf][i];
      v += __shfl_xor(v, 1);
      v += __shfl_xor(v, 2);
      v += __shfl_xor(v, 4);
      v += __shfl_xor(v, 8);
      int row = n0 + wv * 32 + rf * 16 + lk * 4 + i;
      if (lr == 0 && row < NPix)
        wpart[((size_t)b * NPix + row) * 12 + jt] = v;
    }
}

// ---------------- K6: GEMM2 fp16 + fused lsum + fused epilogue --------------
__global__ __launch_bounds__(256, 3) void k_gemm2e(const unsigned short* __restrict__ wbuf,
                                                   const unsigned short* __restrict__ Vg,
                                                   const int* __restrict__ cnts,
                                                   const float* __restrict__ wpart,
                                                   const float* __restrict__ bgproto,
                                                   float* __restrict__ out) {
  int b = blockIdx.z; int M = cnts[4 + b]; if (M > MCAP) return;
  int rt = blockIdx.x, cs = blockIdx.y;
  int t = threadIdx.x, wv = t >> 6, l = t & 63;
  int n0 = rt * 128, c0 = cs * 128;
  int arow0 = n0 + wv * 32 + (l & 15);
  int arow1 = arow0 + 16;
  if (arow0 > NPix - 1) arow0 = NPix - 1;
  if (arow1 > NPix - 1) arow1 = NPix - 1;
  const unsigned short* wr0 = wbuf + ((size_t)b * NPix + arow0) * MCAP + (l >> 4) * 8;
  const unsigned short* wr1 = wbuf + ((size_t)b * NPix + arow1) * MCAP + (l >> 4) * 8;
  const unsigned short* vb  = Vg + ((size_t)b * NC + c0 + (l & 15)) * MCAP + (l >> 4) * 8;

  __shared__ float trans[64][129];    // 33 KB: [c_half][n_local]
  __shared__ float s_linv[128];
  __shared__ float s_bp[128];

  float4v acc[2][8];
#pragma unroll
  for (int rf = 0; rf < 2; ++rf)
#pragma unroll
    for (int cf = 0; cf < 8; ++cf) { float4v z = {0.f,0.f,0.f,0.f}; acc[rf][cf] = z; }

  int nkk = (M + 31) >> 5;
  for (int kk = 0; kk < nkk; ++kk) {
    half8v a0 = *(const half8v*)(wr0 + kk * 32);
    half8v a1 = *(const half8v*)(wr1 + kk * 32);
#pragma unroll
    for (int cf = 0; cf < 8; ++cf) {
      half8v bv = *(const half8v*)(vb + (size_t)cf * 16 * MCAP + kk * 32);
      acc[0][cf] = __builtin_amdgcn_mfma_f32_16x16x32_f16(a0, bv, acc[0][cf], 0, 0, 0);
      acc[1][cf] = __builtin_amdgcn_mfma_f32_16x16x32_f16(a1, bv, acc[1][cf], 0, 0, 0);
    }
  }

  // fused lsum: reduce j-tile partials per row (128-wide tiles now)
  if (t < 128) {
    int row = n0 + t;
    if (row < NPix) {
      const float* wp = wpart + ((size_t)b * NPix + row) * 12;
      int njt = (M + 127) >> 7;
      float s = 0.f;
      for (int j = 0; j < njt; ++j) s += wp[j];
      s_linv[t] = 1.f / s;
    } else s_linv[t] = 0.f;
    s_bp[t] = bgproto[b * NC + c0 + t];
  }

  int g = l >> 4;
  float* outBP = out + NB * NC;
#pragma unroll
  for (int half = 0; half < 2; ++half) {
    __syncthreads();   // half0: covers s_linv/s_bp; half1: trans reads done
#pragma unroll
    for (int cfl = 0; cfl < 4; ++cfl) {
      int cf = half * 4 + cfl;
#pragma unroll
      for (int rf = 0; rf < 2; ++rf)
#pragma unroll
        for (int i = 0; i < 4; ++i) {
          int c_l = cfl * 16 + (l & 15);
          int n_l = wv * 32 + rf * 16 + g * 4 + i;
          trans[c_l][n_l] = acc[rf][cf][i];
        }
    }
    __syncthreads();
#pragma unroll
    for (int it = 0; it < 8; ++it) {
      int idx = t + 256 * it;       // 0..2047
      int c_l = idx >> 5;           // 0..63
      int q   = idx & 31;           // n-quad
      int n   = n0 + q * 4;
      if (n < NPix) {               // NPix%4==0 -> whole quad in range
        float bpv = s_bp[half * 64 + c_l];
        float4 o;
        o.x = bpv * 0.3f + trans[c_l][q * 4 + 0] * s_linv[q * 4 + 0] * 0.7f;
        o.y = bpv * 0.3f + trans[c_l][q * 4 + 1] * s_linv[q * 4 + 1] * 0.7f;
        o.z = bpv * 0.3f + trans[c_l][q * 4 + 2] * s_linv[q * 4 + 2] * 0.7f;
        o.w = bpv * 0.3f + trans[c_l][q * 4 + 3] * s_linv[q * 4 + 3] * 0.7f;
        *(float4*)&outBP[((size_t)b * NC + c0 + half * 64 + c_l) * NPix + n] = o;
      }
    }
  }
}

// ---------------- fallback: gather + fp32 attention (gated) -----------------
__global__ __launch_bounds__(256) void k_gather(const float* __restrict__ feature,
                                                const float* __restrict__ colnorm,
                                                const int* __restrict__ cnts,
                                                const int* __restrict__ bgsel,
                                                float* __restrict__ featn_sel,
                                                float* __restrict__ normsel,
                                                int gate) {
  int b = blockIdx.y;
  int cnt = cnts[4 + b];
  if (gate && cnt <= MCAP) return;
  int jl = threadIdx.x >> 6;
  int lane = threadIdx.x & 63;
  int j = blockIdx.x * 4 + jl;
  if (j >= cnt) return;
  int row = bgsel[b * NPix + j];
  float nrm = colnorm[b * NPix + row];
  float inv = 1.f / nrm;
#pragma unroll
  for (int i = 0; i < 4; ++i) {
    int c = lane + 64 * i;
    featn_sel[((size_t)b * NPix + j) * NC + c] =
        feature[((size_t)b * NC + c) * NPix + row] * inv;
  }
  if (lane == 0) normsel[b * NPix + j] = nrm;
}

__global__ __launch_bounds__(256) void k_attn(const float* __restrict__ feature,
                                              const float* __restrict__ colnorm,
                                              const int* __restrict__ cnts,
                                              const float* __restrict__ featn_sel,
                                              const float* __restrict__ normsel,
                                              const float* __restrict__ bgproto,
                                              float* __restrict__ out,
                                              int gate) {
  int b = blockIdx.y;
  int M = cnts[4 + b];
  if (gate && M <= MCAP) return;
  int tile = blockIdx.x;
  int t = threadIdx.x;
  int rl  = t >> 4;
  int l16 = t & 15;
  int row = tile * 16 + rl;
  const float* feat = feature + (size_t)b * NC * NPix;

  __shared__ float s_k[32][NC];
  __shared__ float s_vn[32];

  float inv_n = 1.f / colnorm[b * NPix + row];
  float q[16];
#pragma unroll
  for (int k = 0; k < 4; ++k)
#pragma unroll
    for (int i = 0; i < 4; ++i) {
      int c = l16 * 4 + 64 * k + i;
      q[k * 4 + i] = feat[(size_t)c * NPix + row] * inv_n;
    }

  float l_acc = 0.f;
  float O[16];
#pragma unroll
  for (int i = 0; i < 16; ++i) O[i] = 0.f;

  for (int kt = 0; kt < M; kt += 32) {
    int jmax = min(32, M - kt);
    __syncthreads();
    for (int u = t; u < 32 * 64; u += 256) {
      int jj = u >> 6;
      int cc = (u & 63) << 2;
      if (jj < jmax)
        *(float4*)&s_k[jj][cc] =
            *(const float4*)&featn_sel[((size_t)b * NPix + kt + jj) * NC + cc];
    }
    if (t < 32) s_vn[t] = (t < jmax) ? normsel[b * NPix + kt + t] : 0.f;
    __syncthreads();

    for (int j = 0; j < jmax; ++j) {
      float kv[16];
      float s = 0.f;
#pragma unroll
      for (int k = 0; k < 4; ++k) {
        float4 v4 = *(const float4*)&s_k[j][l16 * 4 + 64 * k];
        kv[k * 4 + 0] = v4.x; kv[k * 4 + 1] = v4.y;
        kv[k * 4 + 2] = v4.z; kv[k * 4 + 3] = v4.w;
        s += q[k * 4 + 0] * v4.x + q[k * 4 + 1] * v4.y +
             q[k * 4 + 2] * v4.z + q[k * 4 + 3] * v4.w;
      }
      s += __shfl_xor(s, 1);
      s += __shfl_xor(s, 2);
      s += __shfl_xor(s, 4);
      s += __shfl_xor(s, 8);
      float e = __expf(2.f * s - 2.f);
      l_acc += e;
      float ev = e * s_vn[j];
#pragma unroll
      for (int i = 0; i < 16; ++i) O[i] += ev * kv[i];
    }
  }

  float inv_l = 1.f / l_acc;
  float* outBP = out + NB * NC;
  const float* bp = bgproto + b * NC;
#pragma unroll
  for (int k = 0; k < 4; ++k)
#pragma unroll
    for (int i = 0; i < 4; ++i) {
      int c = l16 * 4 + 64 * k + i;
      outBP[((size_t)b * NC + c) * NPix + row] =
          bp[c] * 0.3f + O[k * 4 + i] * inv_l * 0.7f;
    }
}

// ---------------------------------------------------------------------------
extern "C" void kernel_launch(void* const* d_in, const int* in_sizes, int n_in,
                              void* d_out, int out_size, void* d_ws, size_t ws_size,
                              hipStream_t stream) {
  const float* feature = (const float*)d_in[0];
  const float* mask_q  = (const float*)d_in[1];
  float* out = (float*)d_out;
  char* ws = (char*)d_ws;

  const size_t BIG_NEED = 47173760ULL;
  if (ws_size >= BIG_NEED) {
    // big-mode carve (all offsets 16B-aligned, sizes in BYTES):
    float* colnorm   = (float*)(ws + 0);          //    57,600
    float* normsel   = (float*)(ws + 57600);      //    57,600 (fallback)
    float* bgproto   = (float*)(ws + 115200);     //     4,096
    int*   cnts      = (int*)  (ws + 119296);     //       256 slot
    int*   bgsel     = (int*)  (ws + 119552);     //    57,600 -> 177,152
    unsigned char* fgm = (unsigned char*)(ws + 177152);    // 14,400
    unsigned char* bgm = (unsigned char*)(ws + 191552);    // 14,400 -> 205,952
    float* pp        = (float*)(ws + 205952);     //   466,944 -> 672,896
    unsigned short* Vg  = (unsigned short*)(ws + 672896);   //  1,572,864 -> 2,245,760
    unsigned short* Qf  = (unsigned short*)(ws + 2245760);  //  7,372,800 -> 9,618,560
    unsigned short* wbuf = (unsigned short*)(ws + 9618560); // 22,118,400 -> 31,736,960
    float* wpart     = (float*)(ws + 31736960);   //   691,200 -> 32,428,160
    float* featn_sel = (float*)(ws + 32428160);   // 14,745,600 -> 47,173,760 (fallback)

    k_mask    <<<NB,               256, 0, stream>>>(mask_q, fgm, bgm, bgsel, cnts);
    k_normpack<<<dim3(57, NB),     256, 0, stream>>>(feature, fgm, bgm, colnorm, Qf, pp);
    k_vtp     <<<dim3(13, 4, NB),  256, 0, stream>>>(Qf, colnorm, cnts, bgsel, Vg,
                                                     pp, out, bgproto);
    k_gemm1   <<<dim3(29, 6, NB),  256, 0, stream>>>(Qf, cnts, bgsel, wbuf, wpart);
    k_gemm2e  <<<dim3(29, 2, NB),  256, 0, stream>>>(wbuf, Vg, cnts, wpart, bgproto, out);
    // fallback path, active only for batches with M > MCAP
    k_gather  <<<dim3(900, NB),    256, 0, stream>>>(feature, colnorm, cnts, bgsel,
                                                     featn_sel, normsel, 1);
    k_attn    <<<dim3(225, NB),    256, 0, stream>>>(feature, colnorm, cnts, featn_sel,
                                                     normsel, bgproto, out, 1);
  } else {
    // small-ws fallback: round-1 layout + kernels
    float* colnorm  = (float*)(ws + 0);
    float* normsel  = (float*)(ws + 57600);
    float* bgproto  = (float*)(ws + 115200);
    int*   cnts     = (int*)  (ws + 119296);
    int*   bgsel    = (int*)  (ws + 119360);
    unsigned char* fgm = (unsigned char*)(ws + 176960);
    unsigned char* bgm = (unsigned char*)(ws + 191360);
    float* featn_sel = (float*)(ws + 205824);

    k_colnorm<<<dim3(15, NB), 256, 0, stream>>>(feature, colnorm);
    k_mask   <<<NB,           256, 0, stream>>>(mask_q, fgm, bgm, bgsel, cnts);
    k_proto  <<<dim3(NC, NB), 256, 0, stream>>>(feature, fgm, bgm, cnts, out, bgproto);
    k_gather <<<dim3(900, NB),256, 0, stream>>>(feature, colnorm, cnts, bgsel,
                                                featn_sel, normsel, 0);
    k_attn   <<<dim3(225, NB),256, 0, stream>>>(feature, colnorm, cnts, featn_sel,
                                                normsel, bgproto, out, 0);
  }
}

// Round 10
// 91.002 us; speedup vs baseline: 1.5979x; 1.1746x over previous
//
#include <hip/hip_runtime.h>
#include <math.h>
#include <float.h>

#define NPix 3600
#define NC   256
#define NB   4
#define MCAP 768

typedef __attribute__((ext_vector_type(8))) _Float16 half8v;
typedef __attribute__((ext_vector_type(4))) float float4v;

__device__ __forceinline__ unsigned short f2h(float x) {
  _Float16 h = (_Float16)x;           // RTNE
  unsigned short u; __builtin_memcpy(&u, &h, 2); return u;
}
__device__ __forceinline__ float h2f(unsigned short u) {
  _Float16 h; __builtin_memcpy(&h, &u, 2); return (float)h;
}

// async global->LDS DMA, 16B per lane; LDS dest must be wave-uniform base
__device__ __forceinline__ void gld_lds16(const void* g, void* l) {
  __builtin_amdgcn_global_load_lds(
      (const __attribute__((address_space(1))) unsigned int*)g,
      (__attribute__((address_space(3))) unsigned int*)l, 16, 0, 0);
}

// ---------------- K0 (small-ws fallback only): column L2 norms --------------
__global__ __launch_bounds__(256) void k_colnorm(const float* __restrict__ feature,
                                                 float* __restrict__ colnorm) {
  int b = blockIdx.y;
  int n = blockIdx.x * 256 + threadIdx.x;
  if (n >= NPix) return;
  const float* feat = feature + (size_t)b * NC * NPix;
  float acc = 0.f;
#pragma unroll 8
  for (int c = 0; c < NC; ++c) {
    float v = feat[(size_t)c * NPix + n];
    acc += v * v;
  }
  colnorm[b * NPix + n] = sqrtf(acc);
}

// ---------------- top-12 fallback (block-wide iterative argmax, 1024 thr) ---
__device__ void block_top12(const float* __restrict__ p, int t,
                            float* s_rv, int* s_ri, int* s_chosen) {
  for (int k = 0; k < 12; ++k) {
    float best = -FLT_MAX;
    int bi = 0x7fffffff;
    for (int n = t; n < NPix; n += 1024) {
      bool excl = false;
      for (int j = 0; j < k; ++j)
        if (s_chosen[j] == n) excl = true;
      if (!excl) {
        float v = p[n];
        if (v > best || (v == best && n < bi)) { best = v; bi = n; }
      }
    }
    s_rv[t] = best; s_ri[t] = bi;
    __syncthreads();
    for (int d = 512; d > 0; d >>= 1) {
      if (t < d) {
        if (s_rv[t + d] > s_rv[t] ||
            (s_rv[t + d] == s_rv[t] && s_ri[t + d] < s_ri[t])) {
          s_rv[t] = s_rv[t + d]; s_ri[t] = s_ri[t + d];
        }
      }
      __syncthreads();
    }
    if (t == 0) s_chosen[k] = s_ri[0];
    __syncthreads();
  }
  if (t == 0) {
    for (int a = 1; a < 12; ++a) {
      int key = s_chosen[a]; int j = a - 1;
      while (j >= 0 && s_chosen[j] > key) { s_chosen[j + 1] = s_chosen[j]; --j; }
      s_chosen[j + 1] = key;
    }
  }
  __syncthreads();
}

// ---------------- K1: masks + deterministic compaction (ballot scan) --------
__global__ __launch_bounds__(1024) void k_mask(const float* __restrict__ mask_q,
                                               unsigned char* __restrict__ fgm,
                                               unsigned char* __restrict__ bgm,
                                               int* __restrict__ bgsel,
                                               int* __restrict__ cnts) {
  int b = blockIdx.x;
  int t = threadIdx.x;
  int wv = t >> 6, l = t & 63;   // 16 waves
  const float* pred_bg = mask_q + (size_t)b * 2 * NPix;
  const float* pred_fg = pred_bg + NPix;

  __shared__ int   s_wtot[16];
  __shared__ int   s_base[2];
  __shared__ float s_rv[1024];
  __shared__ int   s_ri[1024];
  __shared__ int   s_chosen[12];

  if (t == 0) { s_base[0] = 0; s_base[1] = 0; }
  __syncthreads();

  unsigned long long lmask = (1ull << l) - 1ull;

  for (int chunk = 0; chunk < NPix; chunk += 1024) {
    int n = chunk + t;
    int fgf = 0, bgf = 0;
    if (n < NPix) {
      fgf = pred_fg[n] > 0.5f ? 1 : 0;
      bgf = pred_bg[n] > 0.8f ? 1 : 0;
      fgm[b * NPix + n] = (unsigned char)fgf;
      bgm[b * NPix + n] = (unsigned char)bgf;
    }
    unsigned long long fb = __ballot(fgf != 0);
    unsigned long long bb = __ballot(bgf != 0);
    if (l == 0) s_wtot[wv] = __popcll(fb) | (__popcll(bb) << 16);
    __syncthreads();
    int fsum = 0, bsum = 0, bpre = 0;
#pragma unroll
    for (int w = 0; w < 16; ++w) {
      int v = s_wtot[w];
      if (w < wv) bpre += (v >> 16);
      fsum += v & 0xffff; bsum += (v >> 16);
    }
    if (bgf) {
      int pos = s_base[1] + bpre + (int)__popcll(bb & lmask);
      bgsel[b * NPix + pos] = n;
    }
    __syncthreads();
    if (t == 0) { s_base[0] += fsum; s_base[1] += bsum; }
    __syncthreads();
  }
  int fgcnt = s_base[0];
  int bgcnt = s_base[1];

  if (fgcnt == 0) {
    block_top12(pred_fg, t, s_rv, s_ri, s_chosen);
    if (t < 12) fgm[b * NPix + s_chosen[t]] = 1;
    fgcnt = 12;
    __syncthreads();
  }
  if (bgcnt == 0) {
    block_top12(pred_bg, t, s_rv, s_ri, s_chosen);
    if (t < 12) {
      bgm[b * NPix + s_chosen[t]] = 1;
      bgsel[b * NPix + t] = s_chosen[t];
    }
    bgcnt = 12;
    __syncthreads();
  }
  if (t == 0) { cnts[b] = fgcnt; cnts[4 + b] = bgcnt; }
}

// ---------------- K2 (small-ws fallback only): prototypes -------------------
__global__ __launch_bounds__(256) void k_proto(const float* __restrict__ feature,
                                               const unsigned char* __restrict__ fgm,
                                               const unsigned char* __restrict__ bgm,
                                               const int* __restrict__ cnts,
                                               float* __restrict__ out,
                                               float* __restrict__ bgproto) {
  int c = blockIdx.x, b = blockIdx.y, t = threadIdx.x;
  const float* frow = feature + ((size_t)b * NC + c) * NPix;
  float fs = 0.f, bs = 0.f;
  for (int n = t; n < NPix; n += 256) {
    float v = frow[n];
    fs += v * (float)fgm[b * NPix + n];
    bs += v * (float)bgm[b * NPix + n];
  }
  __shared__ float s1[256], s2[256];
  s1[t] = fs; s2[t] = bs;
  __syncthreads();
  for (int d = 128; d > 0; d >>= 1) {
    if (t < d) { s1[t] += s1[t + d]; s2[t] += s2[t + d]; }
    __syncthreads();
  }
  if (t == 0) {
    out[b * NC + c]     = s1[0] / (float)cnts[b];
    bgproto[b * NC + c] = s2[0] / (float)cnts[4 + b];
  }
}

// ---------------- K3: fused colnorm + fp16 pack + proto partials ------------
__global__ __launch_bounds__(256) void k_normpack(const float* __restrict__ feature,
                                                  const unsigned char* __restrict__ fgm,
                                                  const unsigned char* __restrict__ bgm,
                                                  float* __restrict__ colnorm,
                                                  unsigned short* __restrict__ Qf,
                                                  float* __restrict__ pp) {
  int b = blockIdx.y, nt = blockIdx.x, t = threadIdx.x;
  int n0 = nt * 64;
  __shared__ float s_sq[16][68];
  __shared__ float s_inv[64];
  __shared__ float s_fg[64], s_bg[64];
  __shared__ unsigned int tl[64][65];
  __shared__ float traw[64][65];
  __shared__ float s_red[2][4][64];
  const float* fb = feature + (size_t)b * NC * NPix;

  // phase A: sum of squares
  int p4 = t & 15, cq = t >> 4;
  float sq0 = 0.f, sq1 = 0.f, sq2 = 0.f, sq3 = 0.f;
  if (n0 + 64 <= NPix) {
#pragma unroll
    for (int j = 0; j < 16; ++j) {
      const float* src = fb + (size_t)(cq * 16 + j) * NPix + n0 + p4 * 4;
      float4 v = *(const float4*)src;
      sq0 += v.x * v.x; sq1 += v.y * v.y; sq2 += v.z * v.z; sq3 += v.w * v.w;
    }
  } else {
#pragma unroll
    for (int j = 0; j < 16; ++j) {
      size_t base = (size_t)(cq * 16 + j) * NPix;
      int n = n0 + p4 * 4;
      float v0 = (n + 0 < NPix) ? fb[base + n + 0] : 0.f;
      float v1 = (n + 1 < NPix) ? fb[base + n + 1] : 0.f;
      float v2 = (n + 2 < NPix) ? fb[base + n + 2] : 0.f;
      float v3 = (n + 3 < NPix) ? fb[base + n + 3] : 0.f;
      sq0 += v0 * v0; sq1 += v1 * v1; sq2 += v2 * v2; sq3 += v3 * v3;
    }
  }
  s_sq[cq][p4 * 4 + 0] = sq0;
  s_sq[cq][p4 * 4 + 1] = sq1;
  s_sq[cq][p4 * 4 + 2] = sq2;
  s_sq[cq][p4 * 4 + 3] = sq3;
  __syncthreads();
  if (t < 64) {
    float acc = 0.f;
#pragma unroll
    for (int q = 0; q < 16; ++q) acc += s_sq[q][t];
    float nrm = sqrtf(acc);
    int n = n0 + t;
    s_inv[t] = (n < NPix) ? 1.f / nrm : 0.f;
    if (n < NPix) colnorm[b * NPix + n] = nrm;
    s_fg[t] = (n < NPix) ? (float)fgm[b * NPix + n] : 0.f;
    s_bg[t] = (n < NPix) ? (float)bgm[b * NPix + n] : 0.f;
  }
  __syncthreads();

  // phase B
  unsigned short* QfB = Qf + (size_t)b * NPix * NC;
  int nl = t & 63;
  int nn = n0 + nl;
  bool inr = nn < NPix;
  float invn = s_inv[nl];
  for (int cs = 0; cs < 4; ++cs) {
    int c0 = cs * 64;
#pragma unroll
    for (int i = 0; i < 16; ++i) {
      int cl = (t >> 6) + 4 * i;
      float raw = inr ? fb[(size_t)(c0 + cl) * NPix + nn] : 0.f;
      traw[cl][nl] = raw;
      tl[cl][nl] = (unsigned int)f2h(raw * invn);
    }
    __syncthreads();
#pragma unroll
    for (int i = 0; i < 8; ++i) {
      int idx = t + 256 * i;
      int n = idx >> 5;
      int cp = idx & 31;
      int row = n0 + n;
      if (row < NPix) {
        unsigned int u = (tl[2 * cp][n] & 0xffffu) | (tl[2 * cp + 1][n] << 16);
        *(unsigned int*)&QfB[(size_t)row * NC + c0 + 2 * cp] = u;
      }
    }
    {
      int cl = t & 63, pq = t >> 6;
      float pf = 0.f, pb = 0.f;
#pragma unroll
      for (int k = 0; k < 16; ++k) {
        int p = pq * 16 + k;
        float feat = traw[cl][p];
        pf += feat * s_fg[p];
        pb += feat * s_bg[p];
      }
      s_red[0][pq][cl] = pf;
      s_red[1][pq][cl] = pb;
    }
    __syncthreads();
    if (t < 128) {
      int m = t >> 6, cl = t & 63;
      float s = s_red[m][0][cl] + s_red[m][1][cl] + s_red[m][2][cl] + s_red[m][3][cl];
      pp[((size_t)(b * 57 + nt) * 2 + m) * 256 + c0 + cl] = s;
    }
    __syncthreads();
  }
}

// ---------------- K4: merged GEMM1 + V^T build + proto reduce ---------------
// Flattened grid.x per batch: [0,174) GEMM1 (rt=x%29, jt=x/29);
// [174,222) V^T build (u=x-174: jt=u>>2, cs=u&3); x==222 proto reduce.
// GEMM1: 128x128 tile, gld_lds + source-side XOR swizzle, ascending-K order.
__global__ __launch_bounds__(256) void k_vg(const unsigned short* __restrict__ Qf,
                                            const float* __restrict__ colnorm,
                                            const int* __restrict__ cnts,
                                            const int* __restrict__ bgsel,
                                            unsigned short* __restrict__ Vg,
                                            const float* __restrict__ pp,
                                            float* __restrict__ out,
                                            float* __restrict__ bgproto,
                                            unsigned short* __restrict__ wbuf,
                                            float* __restrict__ wpart) {
  int b = blockIdx.z;
  int x = blockIdx.x;
  int t = threadIdx.x;

  __shared__ __align__(16) char smem[32768];

  if (x == 222) {                 // ---- proto reduce ----
    int c = t;
    float f = 0.f, g = 0.f;
    for (int nt = 0; nt < 57; ++nt) {
      const float* base = pp + (size_t)(b * 57 + nt) * 2 * 256;
      f += base[c];
      g += base[256 + c];
    }
    out[b * NC + c]     = f / (float)cnts[b];
    bgproto[b * NC + c] = g / (float)cnts[4 + b];
    return;
  }

  int M = cnts[4 + b];
  if (M > MCAP) return;

  if (x >= 174) {                 // ---- V^T fp16 build ----
    int u = x - 174;
    int jt = u >> 2, cs = u & 3;
    int j0 = jt * 64, c0 = cs * 64;
    unsigned short* tl = (unsigned short*)smem;   // [64][73]
    const size_t qoff = (size_t)b * NPix * NC;
#pragma unroll
    for (int i = 0; i < 16; ++i) {
      int idx = t + 256 * i; int j = idx >> 6, ch = idx & 63;
      int jg = j0 + j;
      float v = 0.f;
      if (jg < M) {
        int src = bgsel[b * NPix + jg];
        v = h2f(Qf[qoff + (size_t)src * NC + c0 + ch]) * colnorm[b * NPix + src];
      }
      tl[j * 73 + ch] = f2h(v);
    }
    __syncthreads();
#pragma unroll
    for (int i = 0; i < 16; ++i) {
      int idx = t + 256 * i; int ch = idx >> 6, j = idx & 63;
      Vg[((size_t)b * NC + c0 + ch) * MCAP + j0 + j] = tl[j * 73 + ch];
    }
    return;
  }

  // ---- GEMM1 ----
  int rt = x % 29, jt = x / 29;
  if (jt * 128 >= M) return;
  int wv = t >> 6, l = t & 63;
  int n0 = rt * 128, j0 = jt * 128;

  unsigned short* Ah = (unsigned short*)smem;            // [128][64]
  unsigned short* Bh = (unsigned short*)(smem + 32768 / 2);  // [128][64]

  const unsigned short* QfB = Qf + (size_t)b * NPix * NC;

  size_t asrc[4];
  int    aslt[4];
#pragma unroll
  for (int i = 0; i < 4; ++i) {
    int u = i * 256 + wv * 64 + l;           // 0..1023
    int r = u >> 3, sl = u & 7;
    int grow = n0 + r; if (grow > NPix - 1) grow = NPix - 1;
    asrc[i] = (size_t)grow * NC;
    aslt[i] = (sl ^ (r & 7)) << 3;
  }
  size_t bsrc[4];
  int    bslt[4];
#pragma unroll
  for (int i = 0; i < 4; ++i) {
    int u = i * 256 + wv * 64 + l;           // 0..1023
    int r = u >> 3, sl = u & 7;
    int jg = j0 + r;
    int src = (jg < M) ? bgsel[b * NPix + jg] : 0;
    bsrc[i] = (size_t)src * NC;
    bslt[i] = (sl ^ (r & 7)) << 3;
  }

  int lr = l & 15;
  int lk = l >> 4;

  float4v acc[2][8];
#pragma unroll
  for (int rf = 0; rf < 2; ++rf)
#pragma unroll
    for (int cf = 0; cf < 8; ++cf) { float4v z = {0.f,0.f,0.f,0.f}; acc[rf][cf] = z; }

  for (int cc = 0; cc < 4; ++cc) {
    int cbase = cc * 64;
#pragma unroll
    for (int i = 0; i < 4; ++i) {
      int ldso = (i * 256 + wv * 64) * 16;
      gld_lds16(QfB + asrc[i] + cbase + aslt[i], (char*)Ah + ldso);
    }
#pragma unroll
    for (int i = 0; i < 4; ++i) {
      int ldso = (i * 256 + wv * 64) * 16;
      gld_lds16(QfB + bsrc[i] + cbase + bslt[i], (char*)Bh + ldso);
    }
    __syncthreads();   // drains vmcnt -> DMA complete

#pragma unroll
    for (int kk = 0; kk < 2; ++kk) {
      int kslot = kk * 4 + lk;
      half8v ah[2];
#pragma unroll
      for (int rf = 0; rf < 2; ++rf) {
        int r = wv * 32 + rf * 16 + lr;
        int s = (kslot ^ (r & 7)) << 3;
        ah[rf] = *(const half8v*)&Ah[r * 64 + s];
      }
#pragma unroll
      for (int cf = 0; cf < 8; ++cf) {
        int j = cf * 16 + lr;
        int s = (kslot ^ (j & 7)) << 3;
        half8v bh = *(const half8v*)&Bh[j * 64 + s];
#pragma unroll
        for (int rf = 0; rf < 2; ++rf)
          acc[rf][cf] = __builtin_amdgcn_mfma_f32_16x16x32_f16(ah[rf], bh, acc[rf][cf], 0, 0, 0);
      }
    }
    __syncthreads();   // before next-chunk overwrite
  }

  // epilogue: w = exp(2s-2) -> fp16; store + per-row partial sums
  float rs[2][4];
#pragma unroll
  for (int rf = 0; rf < 2; ++rf)
#pragma unroll
    for (int i = 0; i < 4; ++i) rs[rf][i] = 0.f;

#pragma unroll
  for (int rf = 0; rf < 2; ++rf)
#pragma unroll
    for (int cf = 0; cf < 8; ++cf)
#pragma unroll
      for (int i = 0; i < 4; ++i) {
        int row = n0 + wv * 32 + rf * 16 + lk * 4 + i;
        int j = j0 + cf * 16 + lr;
        float s = acc[rf][cf][i];
        unsigned short w16 = (j < M) ? f2h(__expf(2.f * s - 2.f)) : (unsigned short)0;
        if (row < NPix)
          wbuf[((size_t)b * NPix + row) * MCAP + j] = w16;
        rs[rf][i] += h2f(w16);
      }

#pragma unroll
  for (int rf = 0; rf < 2; ++rf)
#pragma unroll
    for (int i = 0; i < 4; ++i) {
      float v = rs[rf][i];
      v += __shfl_xor(v, 1);
      v += __shfl_xor(v, 2);
      v += __shfl_xor(v, 4);
      v += __shfl_xor(v, 8);
      int row = n0 + wv * 32 + rf * 16 + lk * 4 + i;
      if (lr == 0 && row < NPix)
        wpart[((size_t)b * NPix + row) * 12 + jt] = v;
    }
}

// ---------------- K5: GEMM2 fp16 + fused lsum + fused epilogue --------------
__global__ __launch_bounds__(256, 3) void k_gemm2e(const unsigned short* __restrict__ wbuf,
                                                   const unsigned short* __restrict__ Vg,
                                                   const int* __restrict__ cnts,
                                                   const float* __restrict__ wpart,
                                                   const float* __restrict__ bgproto,
                                                   float* __restrict__ out) {
  int b = blockIdx.z; int M = cnts[4 + b]; if (M > MCAP) return;
  int rt = blockIdx.x, cs = blockIdx.y;
  int t = threadIdx.x, wv = t >> 6, l = t & 63;
  int n0 = rt * 128, c0 = cs * 128;
  int arow0 = n0 + wv * 32 + (l & 15);
  int arow1 = arow0 + 16;
  if (arow0 > NPix - 1) arow0 = NPix - 1;
  if (arow1 > NPix - 1) arow1 = NPix - 1;
  const unsigned short* wr0 = wbuf + ((size_t)b * NPix + arow0) * MCAP + (l >> 4) * 8;
  const unsigned short* wr1 = wbuf + ((size_t)b * NPix + arow1) * MCAP + (l >> 4) * 8;
  const unsigned short* vb  = Vg + ((size_t)b * NC + c0 + (l & 15)) * MCAP + (l >> 4) * 8;

  __shared__ float trans[64][129];    // 33 KB: [c_half][n_local]
  __shared__ float s_linv[128];
  __shared__ float s_bp[128];

  float4v acc[2][8];
#pragma unroll
  for (int rf = 0; rf < 2; ++rf)
#pragma unroll
    for (int cf = 0; cf < 8; ++cf) { float4v z = {0.f,0.f,0.f,0.f}; acc[rf][cf] = z; }

  int nkk = (M + 31) >> 5;
  for (int kk = 0; kk < nkk; ++kk) {
    half8v a0 = *(const half8v*)(wr0 + kk * 32);
    half8v a1 = *(const half8v*)(wr1 + kk * 32);
#pragma unroll
    for (int cf = 0; cf < 8; ++cf) {
      half8v bv = *(const half8v*)(vb + (size_t)cf * 16 * MCAP + kk * 32);
      acc[0][cf] = __builtin_amdgcn_mfma_f32_16x16x32_f16(a0, bv, acc[0][cf], 0, 0, 0);
      acc[1][cf] = __builtin_amdgcn_mfma_f32_16x16x32_f16(a1, bv, acc[1][cf], 0, 0, 0);
    }
  }

  // fused lsum: reduce j-tile partials per row (128-wide tiles)
  if (t < 128) {
    int row = n0 + t;
    if (row < NPix) {
      const float* wp = wpart + ((size_t)b * NPix + row) * 12;
      int njt = (M + 127) >> 7;
      float s = 0.f;
      for (int j = 0; j < njt; ++j) s += wp[j];
      s_linv[t] = 1.f / s;
    } else s_linv[t] = 0.f;
    s_bp[t] = bgproto[b * NC + c0 + t];
  }

  int g = l >> 4;
  float* outBP = out + NB * NC;
#pragma unroll
  for (int half = 0; half < 2; ++half) {
    __syncthreads();   // half0: covers s_linv/s_bp; half1: trans reads done
#pragma unroll
    for (int cfl = 0; cfl < 4; ++cfl) {
      int cf = half * 4 + cfl;
#pragma unroll
      for (int rf = 0; rf < 2; ++rf)
#pragma unroll
        for (int i = 0; i < 4; ++i) {
          int c_l = cfl * 16 + (l & 15);
          int n_l = wv * 32 + rf * 16 + g * 4 + i;
          trans[c_l][n_l] = acc[rf][cf][i];
        }
    }
    __syncthreads();
#pragma unroll
    for (int it = 0; it < 8; ++it) {
      int idx = t + 256 * it;       // 0..2047
      int c_l = idx >> 5;           // 0..63
      int q   = idx & 31;           // n-quad
      int n   = n0 + q * 4;
      if (n < NPix) {               // NPix%4==0 -> whole quad in range
        float bpv = s_bp[half * 64 + c_l];
        float4 o;
        o.x = bpv * 0.3f + trans[c_l][q * 4 + 0] * s_linv[q * 4 + 0] * 0.7f;
        o.y = bpv * 0.3f + trans[c_l][q * 4 + 1] * s_linv[q * 4 + 1] * 0.7f;
        o.z = bpv * 0.3f + trans[c_l][q * 4 + 2] * s_linv[q * 4 + 2] * 0.7f;
        o.w = bpv * 0.3f + trans[c_l][q * 4 + 3] * s_linv[q * 4 + 3] * 0.7f;
        *(float4*)&outBP[((size_t)b * NC + c0 + half * 64 + c_l) * NPix + n] = o;
      }
    }
  }
}

// ---------------- fallback: self-normalizing fp32 attention (gated) ---------
__global__ __launch_bounds__(256) void k_attn(const float* __restrict__ feature,
                                              const float* __restrict__ colnorm,
                                              const int* __restrict__ cnts,
                                              const int* __restrict__ bgsel,
                                              const float* __restrict__ bgproto,
                                              float* __restrict__ out,
                                              int gate) {
  int b = blockIdx.y;
  int M = cnts[4 + b];
  if (gate && M <= MCAP) return;
  int tile = blockIdx.x;
  int t = threadIdx.x;
  int rl  = t >> 4;
  int l16 = t & 15;
  int row = tile * 16 + rl;
  const float* feat = feature + (size_t)b * NC * NPix;

  __shared__ float s_k[32][NC];
  __shared__ float s_vn[32];

  float inv_n = 1.f / colnorm[b * NPix + row];
  float q[16];
#pragma unroll
  for (int k = 0; k < 4; ++k)
#pragma unroll
    for (int i = 0; i < 4; ++i) {
      int c = l16 * 4 + 64 * k + i;
      q[k * 4 + i] = feat[(size_t)c * NPix + row] * inv_n;
    }

  float l_acc = 0.f;
  float O[16];
#pragma unroll
  for (int i = 0; i < 16; ++i) O[i] = 0.f;

  for (int kt = 0; kt < M; kt += 32) {
    int jmax = min(32, M - kt);
    __syncthreads();
    for (int u = t; u < 32 * 64; u += 256) {
      int jj = u >> 6;
      int cc = (u & 63) << 2;
      if (jj < jmax) {
        int src = bgsel[b * NPix + kt + jj];
        float inv = 1.f / colnorm[b * NPix + src];
        float4 v;
        v.x = feat[(size_t)(cc + 0) * NPix + src] * inv;
        v.y = feat[(size_t)(cc + 1) * NPix + src] * inv;
        v.z = feat[(size_t)(cc + 2) * NPix + src] * inv;
        v.w = feat[(size_t)(cc + 3) * NPix + src] * inv;
        *(float4*)&s_k[jj][cc] = v;
      }
    }
    if (t < 32)
      s_vn[t] = (t < jmax) ? colnorm[b * NPix + bgsel[b * NPix + kt + t]] : 0.f;
    __syncthreads();

    for (int j = 0; j < jmax; ++j) {
      float kv[16];
      float s = 0.f;
#pragma unroll
      for (int k = 0; k < 4; ++k) {
        float4 v4 = *(const float4*)&s_k[j][l16 * 4 + 64 * k];
        kv[k * 4 + 0] = v4.x; kv[k * 4 + 1] = v4.y;
        kv[k * 4 + 2] = v4.z; kv[k * 4 + 3] = v4.w;
        s += q[k * 4 + 0] * v4.x + q[k * 4 + 1] * v4.y +
             q[k * 4 + 2] * v4.z + q[k * 4 + 3] * v4.w;
      }
      s += __shfl_xor(s, 1);
      s += __shfl_xor(s, 2);
      s += __shfl_xor(s, 4);
      s += __shfl_xor(s, 8);
      float e = __expf(2.f * s - 2.f);
      l_acc += e;
      float ev = e * s_vn[j];
#pragma unroll
      for (int i = 0; i < 16; ++i) O[i] += ev * kv[i];
    }
  }

  float inv_l = 1.f / l_acc;
  float* outBP = out + NB * NC;
  const float* bp = bgproto + b * NC;
#pragma unroll
  for (int k = 0; k < 4; ++k)
#pragma unroll
    for (int i = 0; i < 4; ++i) {
      int c = l16 * 4 + 64 * k + i;
      outBP[((size_t)b * NC + c) * NPix + row] =
          bp[c] * 0.3f + O[k * 4 + i] * inv_l * 0.7f;
    }
}

// ---------------------------------------------------------------------------
extern "C" void kernel_launch(void* const* d_in, const int* in_sizes, int n_in,
                              void* d_out, int out_size, void* d_ws, size_t ws_size,
                              hipStream_t stream) {
  const float* feature = (const float*)d_in[0];
  const float* mask_q  = (const float*)d_in[1];
  float* out = (float*)d_out;
  char* ws = (char*)d_ws;

  const size_t BIG_NEED = 32428160ULL;
  if (ws_size >= BIG_NEED) {
    // big-mode carve (all offsets 16B-aligned, sizes in BYTES):
    float* colnorm   = (float*)(ws + 0);          //    57,600
    float* bgproto   = (float*)(ws + 115200);     //     4,096
    int*   cnts      = (int*)  (ws + 119296);     //       256 slot
    int*   bgsel     = (int*)  (ws + 119552);     //    57,600 -> 177,152
    unsigned char* fgm = (unsigned char*)(ws + 177152);    // 14,400
    unsigned char* bgm = (unsigned char*)(ws + 191552);    // 14,400 -> 205,952
    float* pp        = (float*)(ws + 205952);     //   466,944 -> 672,896
    unsigned short* Vg  = (unsigned short*)(ws + 672896);   //  1,572,864 -> 2,245,760
    unsigned short* Qf  = (unsigned short*)(ws + 2245760);  //  7,372,800 -> 9,618,560
    unsigned short* wbuf = (unsigned short*)(ws + 9618560); // 22,118,400 -> 31,736,960
    float* wpart     = (float*)(ws + 31736960);   //   691,200 -> 32,428,160

    k_mask    <<<NB,               1024, 0, stream>>>(mask_q, fgm, bgm, bgsel, cnts);
    k_normpack<<<dim3(57, NB),     256, 0, stream>>>(feature, fgm, bgm, colnorm, Qf, pp);
    k_vg      <<<dim3(223, 1, NB), 256, 0, stream>>>(Qf, colnorm, cnts, bgsel, Vg,
                                                     pp, out, bgproto, wbuf, wpart);
    k_gemm2e  <<<dim3(29, 2, NB),  256, 0, stream>>>(wbuf, Vg, cnts, wpart, bgproto, out);
    // fallback path, active only for batches with M > MCAP
    k_attn    <<<dim3(225, NB),    256, 0, stream>>>(feature, colnorm, cnts, bgsel,
                                                     bgproto, out, 1);
  } else {
    // small-ws fallback: simple kernels, self-normalizing attention
    float* colnorm  = (float*)(ws + 0);
    float* bgproto  = (float*)(ws + 115200);
    int*   cnts     = (int*)  (ws + 119296);
    int*   bgsel    = (int*)  (ws + 119552);
    unsigned char* fgm = (unsigned char*)(ws + 177152);
    unsigned char* bgm = (unsigned char*)(ws + 191552);

    k_colnorm<<<dim3(15, NB), 256, 0, stream>>>(feature, colnorm);
    k_mask   <<<NB,           1024, 0, stream>>>(mask_q, fgm, bgm, bgsel, cnts);
    k_proto  <<<dim3(NC, NB), 256, 0, stream>>>(feature, fgm, bgm, cnts, out, bgproto);
    k_attn   <<<dim3(225, NB),256, 0, stream>>>(feature, colnorm, cnts, bgsel,
                                                bgproto, out, 0);
  }
}